// Round 15
// baseline (852.979 us; speedup 1.0000x reference)
//
#include <hip/hip_runtime.h>
#include <math.h>
#include <stdint.h>

typedef float f4 __attribute__((ext_vector_type(4)));
typedef float f32x4 __attribute__((ext_vector_type(4)));
typedef short s8 __attribute__((ext_vector_type(8)));  // 8 bf16 (4 VGPRs)

static constexpr int N = 50000;
static constexpr int E = 800000;
static constexpr int D = 128;
static constexpr int SCAN_NB = (N + 255) / 256;        // 196
static constexpr int MBLK = 128;                       // gemm rows/block
static constexpr int GRID_M = (N + MBLK - 1) / MBLK;   // 391
static constexpr int N_PAD = GRID_M * MBLK;            // 50048
static constexpr int WT_PITCH = 136;                   // LDS pad
static constexpr int NSLICE = 16;                      // 8-col slices (1.6 MB each)
static constexpr size_t SL = (size_t)N_PAD * 8;        // slice stride (elems)
static constexpr int AGG_BLOCKS = 1024;
static constexpr int CHUNK = 256;                      // nodes per queue grab

__device__ inline unsigned short f32_bf16_rne(float x) {
    unsigned u = __float_as_uint(x);
    return (unsigned short)((u + 0x7FFF + ((u >> 16) & 1)) >> 16);
}
__device__ inline float bf16_f32(unsigned short h) {
    return __uint_as_float((unsigned)h << 16);
}

// --- int degree histogram ---
__global__ void deg_kernel(const int* __restrict__ src, const int* __restrict__ dst,
                           int* __restrict__ deg_out, int* __restrict__ deg_in) {
    int e = blockIdx.x * 256 + threadIdx.x;
    if (e < E) {
        atomicAdd(&deg_out[src[e]], 1);
        atomicAdd(&deg_in[dst[e]], 1);
    }
}

// --- scan pass 1 (+ fused norms): per-block sums of deg_in ---
__global__ __launch_bounds__(256) void scan_bsum_norm_kernel(
    const int* __restrict__ deg_out, const int* __restrict__ deg_in,
    float* __restrict__ norm_src, float* __restrict__ norm_dst,
    int* __restrict__ bsums) {
    int i = blockIdx.x * 256 + threadIdx.x;
    int v = 0;
    if (i < N) {
        norm_src[i] = rsqrtf(fmaxf((float)deg_out[i], 1.0f));
        norm_dst[i] = rsqrtf(fmaxf((float)deg_in[i], 1.0f));
        v = deg_in[i];
    }
#pragma unroll
    for (int off = 1; off < 64; off <<= 1) v += __shfl_xor(v, off, 64);
    __shared__ int ws[4];
    if ((threadIdx.x & 63) == 0) ws[threadIdx.x >> 6] = v;
    __syncthreads();
    if (threadIdx.x == 0) bsums[blockIdx.x] = ws[0] + ws[1] + ws[2] + ws[3];
}

// --- scan final: block base from bsums (in-block) + rescan -> row_ptr ---
__global__ __launch_bounds__(256) void scan_final_kernel(const int* __restrict__ deg,
                                                         const int* __restrict__ bsums,
                                                         int* __restrict__ row_ptr) {
    __shared__ int s[256];
    __shared__ int base_s;
    int b = blockIdx.x, t = threadIdx.x;

    int bv = (t < b && t < SCAN_NB) ? bsums[t] : 0;
#pragma unroll
    for (int off = 1; off < 64; off <<= 1) bv += __shfl_xor(bv, off, 64);
    __shared__ int wsb[4];
    if ((t & 63) == 0) wsb[t >> 6] = bv;
    __syncthreads();
    if (t == 0) base_s = wsb[0] + wsb[1] + wsb[2] + wsb[3];

    int i = b * 256 + t;
    s[t] = (i < N) ? deg[i] : 0;
    __syncthreads();
    for (int off = 1; off < 256; off <<= 1) {
        int v = (t >= off) ? s[t - off] : 0;
        __syncthreads();
        s[t] += v;
        __syncthreads();
    }
    if (i < N) row_ptr[i + 1] = s[t] + base_s;
    if (i == 0) row_ptr[0] = 0;
}

// --- csr fill (ushort src ids) ---
__global__ void fill_kernel(const int* __restrict__ src, const int* __restrict__ dst,
                            const int* __restrict__ row_ptr, int* __restrict__ cursor,
                            unsigned short* __restrict__ csr_src) {
    int e = blockIdx.x * 256 + threadIdx.x;
    if (e < E) {
        int d = dst[e];
        int pos = row_ptr[d] + atomicAdd(&cursor[d], 1);
        csr_src[pos] = (unsigned short)src[e];
    }
}

// --- gather: hs_t[slice][i][c] = emb[batch[i]][col] * norm_src[i] (slice-major) ---
__global__ void gather_kernel(const int* __restrict__ batch, const float* __restrict__ emb,
                              const float* __restrict__ norm_src, float* __restrict__ hs_t) {
    int gid = blockIdx.x * 256 + threadIdx.x;
    int i = gid >> 5;
    int c = (gid & 31) << 2;
    if (i < N) {
        float s = norm_src[i];
        f4 v = *(const f4*)(emb + (size_t)batch[i] * D + c);
        int slice = c >> 3, cc = c & 7;
        *(f4*)(hs_t + (size_t)slice * SL + (size_t)i * 8 + cc) = v * s;
    }
}

// --- W prep: wt[layer][hi/lo][n][k] = bf16 split of W[k][n] (transposed) ---
__global__ void wprep_kernel(const float* __restrict__ W1, const float* __restrict__ W2,
                             const float* __restrict__ W3, short* __restrict__ wt) {
    int idx = blockIdx.x * 256 + threadIdx.x;
    if (idx >= 3 * D * D) return;
    int l = idx >> 14;
    int e = idx & (D * D - 1);
    int n = e >> 7, k = e & 127;
    const float* W = (l == 0) ? W1 : ((l == 1) ? W2 : W3);
    float w = W[(size_t)k * D + n];
    unsigned short h = f32_bf16_rne(w);
    unsigned short lo = f32_bf16_rne(w - bf16_f32(h));
    wt[(size_t)l * 2 * D * D + (size_t)n * D + k] = (short)h;
    wt[(size_t)l * 2 * D * D + D * D + (size_t)n * D + k] = (short)lo;
}

// --- agg v4: XCC-aware slice queues. Each block reads its physical XCD id
// (s_getreg HW_REG_XCC_ID, HW-verified 0-7 on MI355X) and drains the two
// queues of "its" slices first, then steals (correct under ANY mapping).
// Per-XCD resident set = slice (1.6 MB) + csr (1.6 MB) + row_ptr (0.2 MB)
// < 4 MB L2 -> gathers become L2 hits instead of compulsory fills.
// Lane = 1 node x 8 cols; 4-edge unroll (8 f4 loads in flight); coalesced
// node-consecutive 16B hi/lo writes (slice-major output).
__global__ __launch_bounds__(256) void agg_kernel(
    const int* __restrict__ row_ptr, const unsigned short* __restrict__ csr_src,
    const float* __restrict__ hs_t,
    short* __restrict__ agg_h_t, short* __restrict__ agg_l_t,
    int* __restrict__ qcur) {
    unsigned xcc;
    asm volatile("s_getreg_b32 %0, hwreg(HW_REG_XCC_ID)" : "=s"(xcc));
    int tid = threadIdx.x;
    __shared__ int chunk_s;

    for (int qi = 0; qi < NSLICE; ++qi) {
        int q = ((xcc << 1) + qi) & (NSLICE - 1);
        const float* hsq = hs_t + (size_t)q * SL;
        short* ahq = agg_h_t + (size_t)q * SL;
        short* alq = agg_l_t + (size_t)q * SL;
        while (true) {
            __syncthreads();
            if (tid == 0) chunk_s = atomicAdd(&qcur[q], CHUNK);
            __syncthreads();
            int base = chunk_s;
            if (base >= N) break;
            int node = base + tid;
            if (node < N) {
                int beg = row_ptr[node], end = row_ptr[node + 1];
                f4 a0 = (f4)0.0f, a1 = (f4)0.0f, a2 = (f4)0.0f, a3 = (f4)0.0f;
                f4 b0 = (f4)0.0f, b1 = (f4)0.0f, b2 = (f4)0.0f, b3 = (f4)0.0f;
                int e = beg;
                for (; e + 3 < end; e += 4) {
                    int s0 = csr_src[e];
                    int s1 = csr_src[e + 1];
                    int s2 = csr_src[e + 2];
                    int s3 = csr_src[e + 3];
                    const f4* p0 = (const f4*)(hsq + (size_t)s0 * 8);
                    const f4* p1 = (const f4*)(hsq + (size_t)s1 * 8);
                    const f4* p2 = (const f4*)(hsq + (size_t)s2 * 8);
                    const f4* p3 = (const f4*)(hsq + (size_t)s3 * 8);
                    a0 += p0[0]; b0 += p0[1];
                    a1 += p1[0]; b1 += p1[1];
                    a2 += p2[0]; b2 += p2[1];
                    a3 += p3[0]; b3 += p3[1];
                }
                for (; e < end; ++e) {
                    const f4* p0 = (const f4*)(hsq + (size_t)csr_src[e] * 8);
                    a0 += p0[0]; b0 += p0[1];
                }
                a0 += a1; a2 += a3; a0 += a2;
                b0 += b1; b2 += b3; b0 += b2;

                s8 oh, ol;
#pragma unroll
                for (int j = 0; j < 4; ++j) {
                    unsigned short h = f32_bf16_rne(a0[j]);
                    oh[j] = (short)h;
                    ol[j] = (short)f32_bf16_rne(a0[j] - bf16_f32(h));
                    unsigned short h2 = f32_bf16_rne(b0[j]);
                    oh[j + 4] = (short)h2;
                    ol[j + 4] = (short)f32_bf16_rne(b0[j] - bf16_f32(h2));
                }
                *(s8*)(ahq + (size_t)node * 8) = oh;
                *(s8*)(alq + (size_t)node * 8) = ol;
            }
        }
    }
}

// --- MFMA GEMM: 128x128 per block; 512 thr = 8 waves. A from slice-major
// agg_t (slice = kt*4+lg, contiguous s8 per fragment). 3-term bf16 split.
// post != null => output is next layer's hs_t (slice-major); else row-major out.
__global__ __launch_bounds__(512, 2) void gemm_mfma_kernel(
    const short* __restrict__ Ah, const short* __restrict__ Al,
    const short* __restrict__ wth,
    const float* __restrict__ bias, const float* __restrict__ norm_dst,
    const float* __restrict__ post, float* __restrict__ out) {
    __shared__ short wt_h[D * WT_PITCH];   // 34816 B
    __shared__ short wt_l[D * WT_PITCH];   // 34816 B

    int tid = threadIdx.x;
    const short* gh = wth;
    const short* gl = wth + (size_t)D * D;

#pragma unroll
    for (int it = 0; it < 4; ++it) {
        int c = tid + it * 512;            // 2048 chunks of 8 shorts
        int n = c >> 4, kc = c & 15;
        *(s8*)(&wt_h[n * WT_PITCH + kc * 8]) = *(const s8*)(gh + (size_t)n * D + kc * 8);
        *(s8*)(&wt_l[n * WT_PITCH + kc * 8]) = *(const s8*)(gl + (size_t)n * D + kc * 8);
    }
    __syncthreads();

    int wv = tid >> 6;                     // 0..7
    int lane = tid & 63;
    int lg = lane >> 4;
    int lr = lane & 15;

    int arow = blockIdx.x * MBLK + wv * 16 + lr;

    f32x4 acc[8];
#pragma unroll
    for (int nt = 0; nt < 8; ++nt) acc[nt] = (f32x4)0.0f;

#pragma unroll
    for (int kt = 0; kt < 4; ++kt) {
        int slice = kt * 4 + lg;
        s8 ah = *(const s8*)(Ah + (size_t)slice * SL + (size_t)arow * 8);
        s8 al = *(const s8*)(Al + (size_t)slice * SL + (size_t)arow * 8);
        int ko = kt * 32 + lg * 8;
#pragma unroll
        for (int nt = 0; nt < 8; ++nt) {
            int bidx = (nt * 16 + lr) * WT_PITCH + ko;
            s8 bh = *(const s8*)(&wt_h[bidx]);
            s8 bl = *(const s8*)(&wt_l[bidx]);
            acc[nt] = __builtin_amdgcn_mfma_f32_16x16x32_bf16(ah, bh, acc[nt], 0, 0, 0);
            acc[nt] = __builtin_amdgcn_mfma_f32_16x16x32_bf16(al, bh, acc[nt], 0, 0, 0);
            acc[nt] = __builtin_amdgcn_mfma_f32_16x16x32_bf16(ah, bl, acc[nt], 0, 0, 0);
        }
    }

    int r0 = blockIdx.x * MBLK + wv * 16 + lg * 4;
    float nd[4], ps[4];
#pragma unroll
    for (int i = 0; i < 4; ++i) {
        int gr = r0 + i;
        nd[i] = (gr < N) ? norm_dst[gr] : 0.0f;
        ps[i] = (gr < N) ? (post ? post[gr] : 1.0f) : 0.0f;
    }
#pragma unroll
    for (int nt = 0; nt < 8; ++nt) {
        int col = nt * 16 + lr;
        float bv = bias[col];
#pragma unroll
        for (int i = 0; i < 4; ++i) {
            int gr = r0 + i;
            if (gr < N) {
                float v = fmaxf(acc[nt][i] * nd[i] + bv, 0.0f) * ps[i];
                if (post) {
                    int slice = col >> 3, cc = col & 7;
                    out[(size_t)slice * SL + (size_t)gr * 8 + cc] = v;
                } else {
                    out[(size_t)gr * D + col] = v;
                }
            }
        }
    }
}

extern "C" void kernel_launch(void* const* d_in, const int* in_sizes, int n_in,
                              void* d_out, int out_size, void* d_ws, size_t ws_size,
                              hipStream_t stream) {
    const int*   batch = (const int*)d_in[0];
    const int*   src   = (const int*)d_in[1];
    const int*   dst   = (const int*)d_in[2];
    const float* emb   = (const float*)d_in[3];
    const float* W1    = (const float*)d_in[4];
    const float* b1    = (const float*)d_in[5];
    const float* W2    = (const float*)d_in[6];
    const float* b2    = (const float*)d_in[7];
    const float* W3    = (const float*)d_in[8];
    const float* b3    = (const float*)d_in[9];
    float* out = (float*)d_out;

    // ws layout: norm_src[N] | norm_dst[N] | row_ptr[N+1] | csr_src[E ushort]
    //            | hs_t[16][N_PAD][8] | agg_h_t | agg_l_t | wt | qcur[48]
    // Transients (deg_out, deg_in, cursor, bsums) alias agg_h_t (last read by
    // fill, before agg L1 writes it). gemm mid-layers write hs_t in place.
    float*          norm_src = (float*)d_ws;
    float*          norm_dst = norm_src + N;
    int*            row_ptr  = (int*)(norm_dst + N);
    unsigned short* csr_src  = (unsigned short*)(row_ptr + (N + 1));
    float*          hs_t     = (float*)((((uintptr_t)(csr_src + E)) + 15) & ~(uintptr_t)15);
    short*          agg_h_t  = (short*)(hs_t + (size_t)NSLICE * SL);
    short*          agg_l_t  = agg_h_t + (size_t)NSLICE * SL;
    short*          wt       = agg_l_t + (size_t)NSLICE * SL;
    int*            qcur     = (int*)(wt + (size_t)3 * 2 * D * D);
    int*            deg_out  = (int*)agg_h_t;     // transient
    int*            deg_in   = deg_out + N;
    int*            cursor   = deg_in + N;
    int*            bsums    = cursor + N;

    hipMemsetAsync(deg_out, 0, 3 * (size_t)N * sizeof(int), stream);
    hipMemsetAsync(qcur, 0, 3 * NSLICE * sizeof(int), stream);
    deg_kernel<<<(E + 255) / 256, 256, 0, stream>>>(src, dst, deg_out, deg_in);
    scan_bsum_norm_kernel<<<SCAN_NB, 256, 0, stream>>>(deg_out, deg_in,
                                                       norm_src, norm_dst, bsums);
    scan_final_kernel<<<SCAN_NB, 256, 0, stream>>>(deg_in, bsums, row_ptr);
    fill_kernel<<<(E + 255) / 256, 256, 0, stream>>>(src, dst, row_ptr, cursor,
                                                     csr_src);
    gather_kernel<<<((size_t)N * 32 + 255) / 256, 256, 0, stream>>>(batch, emb,
                                                                    norm_src, hs_t);
    wprep_kernel<<<(3 * D * D + 255) / 256, 256, 0, stream>>>(W1, W2, W3, wt);

    const float* bs[3] = {b1, b2, b3};
    for (int l = 0; l < 3; ++l) {
        bool last = (l == 2);
        agg_kernel<<<AGG_BLOCKS, 256, 0, stream>>>(
            row_ptr, csr_src, hs_t, agg_h_t, agg_l_t, qcur + l * NSLICE);
        gemm_mfma_kernel<<<GRID_M, 512, 0, stream>>>(
            agg_h_t, agg_l_t, wt + (size_t)l * 2 * D * D, bs[l], norm_dst,
            last ? nullptr : norm_src,
            last ? out : hs_t);
    }
}

// Round 16
// 436.486 us; speedup vs baseline: 1.9542x; 1.9542x over previous
//
#include <hip/hip_runtime.h>
#include <math.h>

typedef float f4 __attribute__((ext_vector_type(4)));
typedef float f32x4 __attribute__((ext_vector_type(4)));
typedef short s8 __attribute__((ext_vector_type(8)));  // 8 bf16 (4 VGPRs)
typedef short s4 __attribute__((ext_vector_type(4)));  // 4 bf16 (2 VGPRs)

static constexpr int N = 50000;
static constexpr int E = 800000;
static constexpr int D = 128;
static constexpr int SCAN_NB = (N + 255) / 256;        // 196
static constexpr int MBLK = 128;                       // gemm rows/block
static constexpr int GRID_M = (N + MBLK - 1) / MBLK;   // 391
static constexpr int N_PAD = GRID_M * MBLK;            // 50048
static constexpr int WT_PITCH = 136;                   // LDS pad
static constexpr int NCH = 16;                         // edge chunks
static constexpr int NRG = 16;                         // node ranges
static constexpr int EPC = E / NCH;                    // 50000 edges/chunk
static constexpr int RSZ = N / NRG;                    // 3125 nodes/range

__device__ inline unsigned short f32_bf16_rne(float x) {
    unsigned u = __float_as_uint(x);
    return (unsigned short)((u + 0x7FFF + ((u >> 16) & 1)) >> 16);
}
__device__ inline float bf16_f32(unsigned short h) {
    return __uint_as_float((unsigned)h << 16);
}

// --- histogram via LDS (no global atomics): block (c,r) counts chunk c's
// src/dst ids falling in range r. Partials fully overwritten every call.
__global__ __launch_bounds__(256) void hist_kernel(
    const int* __restrict__ src, const int* __restrict__ dst,
    int* __restrict__ partial_src, int* __restrict__ partial_dst) {
    __shared__ int hsrc[RSZ];
    __shared__ int hdst[RSZ];
    int b = blockIdx.x;
    int c = b >> 4, r = b & 15;
    int tid = threadIdx.x;
    for (int j = tid; j < RSZ; j += 256) { hsrc[j] = 0; hdst[j] = 0; }
    __syncthreads();
    int rlo = r * RSZ, rhi = rlo + RSZ;
    int ebase = c * EPC;
    for (int e = ebase + tid; e < ebase + EPC; e += 256) {
        int s = src[e], d = dst[e];
        if (s >= rlo && s < rhi) atomicAdd(&hsrc[s - rlo], 1);
        if (d >= rlo && d < rhi) atomicAdd(&hdst[d - rlo], 1);
    }
    __syncthreads();
    for (int j = tid; j < RSZ; j += 256) {
        partial_src[(size_t)c * N + rlo + j] = hsrc[j];
        partial_dst[(size_t)c * N + rlo + j] = hdst[j];
    }
}

// --- reduce partials -> degrees + norms; turn partial_dst into per-chunk
// exclusive prefixes (for atomic-free fill); block sums of deg_in for scan ---
__global__ __launch_bounds__(256) void reduce_norm_kernel(
    const int* __restrict__ partial_src, int* __restrict__ partial_dst,
    float* __restrict__ norm_src, float* __restrict__ norm_dst,
    int* __restrict__ deg_in, int* __restrict__ bsums) {
    int i = blockIdx.x * 256 + threadIdx.x;
    int din = 0;
    if (i < N) {
        int dout = 0;
#pragma unroll
        for (int c = 0; c < NCH; ++c) dout += partial_src[(size_t)c * N + i];
        int run = 0;
#pragma unroll
        for (int c = 0; c < NCH; ++c) {
            int v = partial_dst[(size_t)c * N + i];
            partial_dst[(size_t)c * N + i] = run;
            run += v;
        }
        din = run;
        deg_in[i] = din;
        norm_src[i] = rsqrtf(fmaxf((float)dout, 1.0f));
        norm_dst[i] = rsqrtf(fmaxf((float)din, 1.0f));
    }
    int v = din;
#pragma unroll
    for (int off = 1; off < 64; off <<= 1) v += __shfl_xor(v, off, 64);
    __shared__ int ws[4];
    if ((threadIdx.x & 63) == 0) ws[threadIdx.x >> 6] = v;
    __syncthreads();
    if (threadIdx.x == 0) bsums[blockIdx.x] = ws[0] + ws[1] + ws[2] + ws[3];
}

// --- scan final: block base from bsums (in-block) + rescan -> row_ptr ---
__global__ __launch_bounds__(256) void scan_final_kernel(const int* __restrict__ deg,
                                                         const int* __restrict__ bsums,
                                                         int* __restrict__ row_ptr) {
    __shared__ int s[256];
    __shared__ int base_s;
    int b = blockIdx.x, t = threadIdx.x;

    int bv = (t < b && t < SCAN_NB) ? bsums[t] : 0;
#pragma unroll
    for (int off = 1; off < 64; off <<= 1) bv += __shfl_xor(bv, off, 64);
    __shared__ int wsb[4];
    if ((t & 63) == 0) wsb[t >> 6] = bv;
    __syncthreads();
    if (t == 0) base_s = wsb[0] + wsb[1] + wsb[2] + wsb[3];

    int i = b * 256 + t;
    s[t] = (i < N) ? deg[i] : 0;
    __syncthreads();
    for (int off = 1; off < 256; off <<= 1) {
        int v = (t >= off) ? s[t - off] : 0;
        __syncthreads();
        s[t] += v;
        __syncthreads();
    }
    if (i < N) row_ptr[i + 1] = s[t] + base_s;
    if (i == 0) row_ptr[0] = 0;
}

// --- fill via LDS cursors (no global atomics): block (c,r) places chunk c's
// edges with dst in range r at row_ptr[d] + pfx_dst[c][d] + lds_cursor++ ---
__global__ __launch_bounds__(256) void fill_kernel(
    const int* __restrict__ src, const int* __restrict__ dst,
    const int* __restrict__ row_ptr, const int* __restrict__ pfx_dst,
    unsigned short* __restrict__ csr_src) {
    __shared__ int cur[RSZ];
    int b = blockIdx.x;
    int c = b >> 4, r = b & 15;
    int tid = threadIdx.x;
    for (int j = tid; j < RSZ; j += 256) cur[j] = 0;
    __syncthreads();
    int rlo = r * RSZ, rhi = rlo + RSZ;
    int ebase = c * EPC;
    for (int e = ebase + tid; e < ebase + EPC; e += 256) {
        int s = src[e], d = dst[e];
        if (d >= rlo && d < rhi) {
            int pos = row_ptr[d] + pfx_dst[(size_t)c * N + d]
                    + atomicAdd(&cur[d - rlo], 1);
            csr_src[pos] = (unsigned short)s;
        }
    }
}

// --- hs[i] = emb[batch[i]] * norm_src[i] ---
__global__ void gather_kernel(const int* __restrict__ batch, const float* __restrict__ emb,
                              const float* __restrict__ norm_src, float* __restrict__ hs) {
    int gid = blockIdx.x * 256 + threadIdx.x;
    int i = gid >> 5;
    int c = (gid & 31) << 2;
    if (i < N) {
        float s = norm_src[i];
        f4 v = *(const f4*)(emb + (size_t)batch[i] * D + c);
        *(f4*)(hs + (size_t)i * D + c) = v * s;
    }
}

// --- agg (R14 champion): 1 wave/node, 2 edge-groups x 8-deep; bf16 hi/lo out.
// FETCH = compulsory 8 XCD x (25.6 MB table + csr stream) @ ~3.7 TB/s fill.
__global__ void agg_kernel(const int* __restrict__ row_ptr,
                           const unsigned short* __restrict__ csr_src,
                           const float* __restrict__ hs,
                           short* __restrict__ agg_h, short* __restrict__ agg_l) {
    int gid = blockIdx.x * 256 + threadIdx.x;
    int node = gid >> 6;
    if (node >= N) return;
    int lane = threadIdx.x & 63;
    int grp = lane >> 5;
    int col = (lane & 31) << 2;
    int beg = row_ptr[node], end = row_ptr[node + 1];

    f4 a0 = (f4)0.0f, a1 = (f4)0.0f, a2 = (f4)0.0f, a3 = (f4)0.0f;
    f4 a4 = (f4)0.0f, a5 = (f4)0.0f, a6 = (f4)0.0f, a7 = (f4)0.0f;
    int e = beg + grp;
    for (; e + 14 < end; e += 16) {
        int s0 = csr_src[e];
        int s1 = csr_src[e + 2];
        int s2 = csr_src[e + 4];
        int s3 = csr_src[e + 6];
        int s4 = csr_src[e + 8];
        int s5 = csr_src[e + 10];
        int s6 = csr_src[e + 12];
        int s7 = csr_src[e + 14];
        a0 += *(const f4*)(hs + (size_t)s0 * D + col);
        a1 += *(const f4*)(hs + (size_t)s1 * D + col);
        a2 += *(const f4*)(hs + (size_t)s2 * D + col);
        a3 += *(const f4*)(hs + (size_t)s3 * D + col);
        a4 += *(const f4*)(hs + (size_t)s4 * D + col);
        a5 += *(const f4*)(hs + (size_t)s5 * D + col);
        a6 += *(const f4*)(hs + (size_t)s6 * D + col);
        a7 += *(const f4*)(hs + (size_t)s7 * D + col);
    }
    for (; e < end; e += 2)
        a0 += *(const f4*)(hs + (size_t)csr_src[e] * D + col);
    a0 += a1; a2 += a3; a4 += a5; a6 += a7;
    a0 += a2; a4 += a6;
    a0 += a4;

    f4 o;
#pragma unroll
    for (int j = 0; j < 4; ++j)
        o[j] = a0[j] + __shfl_xor(a0[j], 32, 64);
    if (grp == 0) {
        s4 oh, ol;
#pragma unroll
        for (int j = 0; j < 4; ++j) {
            unsigned short h = f32_bf16_rne(o[j]);
            oh[j] = (short)h;
            ol[j] = (short)f32_bf16_rne(o[j] - bf16_f32(h));
        }
        *(s4*)(agg_h + (size_t)node * D + col) = oh;
        *(s4*)(agg_l + (size_t)node * D + col) = ol;
    }
}

// --- W prep: wt[layer][hi/lo][n][k] = bf16 split of W[k][n] (transposed) ---
__global__ void wprep_kernel(const float* __restrict__ W1, const float* __restrict__ W2,
                             const float* __restrict__ W3, short* __restrict__ wt) {
    int idx = blockIdx.x * 256 + threadIdx.x;
    if (idx >= 3 * D * D) return;
    int l = idx >> 14;
    int e = idx & (D * D - 1);
    int n = e >> 7, k = e & 127;
    const float* W = (l == 0) ? W1 : ((l == 1) ? W2 : W3);
    float w = W[(size_t)k * D + n];
    unsigned short h = f32_bf16_rne(w);
    unsigned short lo = f32_bf16_rne(w - bf16_f32(h));
    wt[(size_t)l * 2 * D * D + (size_t)n * D + k] = (short)h;
    wt[(size_t)l * 2 * D * D + D * D + (size_t)n * D + k] = (short)lo;
}

// --- MFMA GEMM (R14): 128x128 per block; 512 thr = 8 waves; 3-term bf16 split ---
__global__ __launch_bounds__(512, 2) void gemm_mfma_kernel(
    const short* __restrict__ Ah, const short* __restrict__ Al,
    const short* __restrict__ wth,
    const float* __restrict__ bias, const float* __restrict__ norm_dst,
    const float* __restrict__ post, float* __restrict__ out) {
    __shared__ short wt_h[D * WT_PITCH];   // 34816 B
    __shared__ short wt_l[D * WT_PITCH];   // 34816 B

    int tid = threadIdx.x;
    const short* gh = wth;
    const short* gl = wth + (size_t)D * D;

#pragma unroll
    for (int it = 0; it < 4; ++it) {
        int c = tid + it * 512;            // 2048 chunks of 8 shorts
        int n = c >> 4, kc = c & 15;
        *(s8*)(&wt_h[n * WT_PITCH + kc * 8]) = *(const s8*)(gh + (size_t)n * D + kc * 8);
        *(s8*)(&wt_l[n * WT_PITCH + kc * 8]) = *(const s8*)(gl + (size_t)n * D + kc * 8);
    }
    __syncthreads();

    int wv = tid >> 6;                     // 0..7
    int lane = tid & 63;
    int lg = lane >> 4;
    int lr = lane & 15;

    int arow = blockIdx.x * MBLK + wv * 16 + lr;
    const short* ahp = Ah + (size_t)arow * D;
    const short* alp = Al + (size_t)arow * D;

    f32x4 acc[8];
#pragma unroll
    for (int nt = 0; nt < 8; ++nt) acc[nt] = (f32x4)0.0f;

#pragma unroll
    for (int kt = 0; kt < 4; ++kt) {
        int ko = kt * 32 + lg * 8;
        s8 ah = *(const s8*)(ahp + ko);
        s8 al = *(const s8*)(alp + ko);
#pragma unroll
        for (int nt = 0; nt < 8; ++nt) {
            int bidx = (nt * 16 + lr) * WT_PITCH + ko;
            s8 bh = *(const s8*)(&wt_h[bidx]);
            s8 bl = *(const s8*)(&wt_l[bidx]);
            acc[nt] = __builtin_amdgcn_mfma_f32_16x16x32_bf16(ah, bh, acc[nt], 0, 0, 0);
            acc[nt] = __builtin_amdgcn_mfma_f32_16x16x32_bf16(al, bh, acc[nt], 0, 0, 0);
            acc[nt] = __builtin_amdgcn_mfma_f32_16x16x32_bf16(ah, bl, acc[nt], 0, 0, 0);
        }
    }

    int r0 = blockIdx.x * MBLK + wv * 16 + lg * 4;
    float nd[4], ps[4];
#pragma unroll
    for (int i = 0; i < 4; ++i) {
        int gr = r0 + i;
        nd[i] = (gr < N) ? norm_dst[gr] : 0.0f;
        ps[i] = (gr < N) ? (post ? post[gr] : 1.0f) : 0.0f;
    }
#pragma unroll
    for (int nt = 0; nt < 8; ++nt) {
        int col = nt * 16 + lr;
        float bv = bias[col];
#pragma unroll
        for (int i = 0; i < 4; ++i) {
            int gr = r0 + i;
            if (gr < N) {
                float v = fmaxf(acc[nt][i] * nd[i] + bv, 0.0f) * ps[i];
                out[(size_t)gr * D + col] = v;
            }
        }
    }
}

extern "C" void kernel_launch(void* const* d_in, const int* in_sizes, int n_in,
                              void* d_out, int out_size, void* d_ws, size_t ws_size,
                              hipStream_t stream) {
    const int*   batch = (const int*)d_in[0];
    const int*   src   = (const int*)d_in[1];
    const int*   dst   = (const int*)d_in[2];
    const float* emb   = (const float*)d_in[3];
    const float* W1    = (const float*)d_in[4];
    const float* b1    = (const float*)d_in[5];
    const float* W2    = (const float*)d_in[6];
    const float* b2    = (const float*)d_in[7];
    const float* W3    = (const float*)d_in[8];
    const float* b3    = (const float*)d_in[9];
    float* out = (float*)d_out;

    // ws layout (4B elems): norm_src[N] | norm_dst[N] | row_ptr[N+1] | csr_src[E ushort]
    //                       | hs[N_PAD*D] | agg_h[N_PAD*D sh] | agg_l[N_PAD*D sh] | wt
    // gemm writes hs in place (agg fully consumed it before gemm runs).
    // Build transients (partial_src[16N], partial_dst[16N], deg_in[N], bsums) alias
    // the agg_h/agg_l region (6.6 MB < 25.6 MB): last read by fill/scan, before
    // agg layer-1 writes agg. No memsets needed — everything fully overwritten.
    float*          norm_src    = (float*)d_ws;
    float*          norm_dst    = norm_src + N;
    int*            row_ptr     = (int*)(norm_dst + N);
    unsigned short* csr_src     = (unsigned short*)(row_ptr + (N + 1));
    float*          hs          = (float*)(csr_src + E) + 2;  // 16B alignment
    short*          agg_h       = (short*)(hs + (size_t)N_PAD * D);
    short*          agg_l       = agg_h + (size_t)N_PAD * D;
    short*          wt          = agg_l + (size_t)N_PAD * D;
    int*            partial_src = (int*)agg_h;            // transient 16N
    int*            partial_dst = partial_src + (size_t)NCH * N;  // 16N
    int*            deg_in      = partial_dst + (size_t)NCH * N;  // N
    int*            bsums       = deg_in + N;                     // SCAN_NB

    hist_kernel<<<NCH * NRG, 256, 0, stream>>>(src, dst, partial_src, partial_dst);
    reduce_norm_kernel<<<SCAN_NB, 256, 0, stream>>>(partial_src, partial_dst,
                                                    norm_src, norm_dst, deg_in, bsums);
    scan_final_kernel<<<SCAN_NB, 256, 0, stream>>>(deg_in, bsums, row_ptr);
    fill_kernel<<<NCH * NRG, 256, 0, stream>>>(src, dst, row_ptr, partial_dst,
                                               csr_src);
    gather_kernel<<<((size_t)N * 32 + 255) / 256, 256, 0, stream>>>(batch, emb,
                                                                    norm_src, hs);
    wprep_kernel<<<(3 * D * D + 255) / 256, 256, 0, stream>>>(W1, W2, W3, wt);

    const float* bs[3] = {b1, b2, b3};
    for (int l = 0; l < 3; ++l) {
        bool last = (l == 2);
        agg_kernel<<<((size_t)N * 64 + 255) / 256, 256, 0, stream>>>(
            row_ptr, csr_src, hs, agg_h, agg_l);
        gemm_mfma_kernel<<<GRID_M, 512, 0, stream>>>(
            agg_h, agg_l, wt + (size_t)l * 2 * D * D, bs[l], norm_dst,
            last ? nullptr : norm_src,
            last ? out : hs);
    }
}

// Round 17
// 333.774 us; speedup vs baseline: 2.5556x; 1.3077x over previous
//
#include <hip/hip_runtime.h>
#include <math.h>

typedef float f4 __attribute__((ext_vector_type(4)));
typedef float f32x4 __attribute__((ext_vector_type(4)));
typedef short s8 __attribute__((ext_vector_type(8)));  // 8 bf16 (4 VGPRs)
typedef short s4 __attribute__((ext_vector_type(4)));  // 4 bf16 (2 VGPRs)

static constexpr int N = 50000;
static constexpr int E = 800000;
static constexpr int D = 128;
static constexpr int SCAN_NB = (N + 255) / 256;        // 196
static constexpr int MBLK = 128;                       // gemm rows/block
static constexpr int GRID_M = (N + MBLK - 1) / MBLK;   // 391
static constexpr int N_PAD = GRID_M * MBLK;            // 50048
static constexpr int WT_PITCH = 136;                   // LDS pad
static constexpr int HG = 64;                          // hist/fill blocks per stream
static constexpr int EPB = E / HG;                     // 12500 edges/block
static constexpr int PACK = N / 2;                     // 25000 packed u32 (2 u16 each)

__device__ inline unsigned short f32_bf16_rne(float x) {
    unsigned u = __float_as_uint(x);
    return (unsigned short)((u + 0x7FFF + ((u >> 16) & 1)) >> 16);
}
__device__ inline float bf16_f32(unsigned short h) {
    return __uint_as_float((unsigned)h << 16);
}

// --- full-range LDS histogram (packed u16 pairs, 100 KB LDS, zero global
// atomics): block b<HG histograms src over its 12500-edge chunk; b>=HG dst.
// Max per-block count 12500 < 32768 -> no cross-halfword carry.
__global__ __launch_bounds__(256) void hist_kernel(
    const int* __restrict__ src, const int* __restrict__ dst,
    unsigned* __restrict__ psrc, unsigned* __restrict__ pdst) {
    __shared__ unsigned h[PACK];
    int b = blockIdx.x;
    int tid = threadIdx.x;
    bool isd = b >= HG;
    int bb = isd ? b - HG : b;
    const int* ids = isd ? dst : src;
    for (int j = tid; j < PACK; j += 256) h[j] = 0;
    __syncthreads();
    int ebase = bb * EPB;
    for (int e = ebase + tid; e < ebase + EPB; e += 256) {
        int v = ids[e];
        atomicAdd(&h[v >> 1], 1u << ((v & 1) << 4));
    }
    __syncthreads();
    unsigned* out = (isd ? pdst : psrc) + (size_t)bb * PACK;
    for (int j = tid; j < PACK; j += 256) out[j] = h[j];
}

// --- reduce partial counts -> degrees, norms, deg_in, per-block sums ---
__global__ __launch_bounds__(256) void reduce_norm_kernel(
    const unsigned* __restrict__ psrc, const unsigned* __restrict__ pdst,
    float* __restrict__ norm_src, float* __restrict__ norm_dst,
    int* __restrict__ deg_in, int* __restrict__ bsums) {
    int i = blockIdx.x * 256 + threadIdx.x;
    int din = 0;
    if (i < N) {
        int sh = (i & 1) << 4;
        int j = i >> 1;
        int dout = 0;
#pragma unroll 8
        for (int b = 0; b < HG; ++b) {
            dout += (psrc[(size_t)b * PACK + j] >> sh) & 0xFFFF;
            din  += (pdst[(size_t)b * PACK + j] >> sh) & 0xFFFF;
        }
        deg_in[i] = din;
        norm_src[i] = rsqrtf(fmaxf((float)dout, 1.0f));
        norm_dst[i] = rsqrtf(fmaxf((float)din, 1.0f));
    }
    int v = din;
#pragma unroll
    for (int off = 1; off < 64; off <<= 1) v += __shfl_xor(v, off, 64);
    __shared__ int ws[4];
    if ((threadIdx.x & 63) == 0) ws[threadIdx.x >> 6] = v;
    __syncthreads();
    if (threadIdx.x == 0) bsums[blockIdx.x] = ws[0] + ws[1] + ws[2] + ws[3];
}

// --- convert pdst counts -> per-chunk exclusive prefixes (in place, packed).
// One thread per u32 (2 nodes) -> no RMW conflicts. Runs AFTER reduce_norm.
__global__ __launch_bounds__(256) void prefix_kernel(unsigned* __restrict__ pdst) {
    int j = blockIdx.x * 256 + threadIdx.x;
    if (j >= PACK) return;
    unsigned run0 = 0, run1 = 0;
#pragma unroll 8
    for (int c = 0; c < HG; ++c) {
        unsigned u = pdst[(size_t)c * PACK + j];
        pdst[(size_t)c * PACK + j] = run0 | (run1 << 16);
        run0 += u & 0xFFFF;
        run1 += u >> 16;
    }
}

// --- scan final: block base from bsums (in-block) + rescan -> row_ptr ---
__global__ __launch_bounds__(256) void scan_final_kernel(const int* __restrict__ deg,
                                                         const int* __restrict__ bsums,
                                                         int* __restrict__ row_ptr) {
    __shared__ int s[256];
    __shared__ int base_s;
    int b = blockIdx.x, t = threadIdx.x;

    int bv = (t < b && t < SCAN_NB) ? bsums[t] : 0;
#pragma unroll
    for (int off = 1; off < 64; off <<= 1) bv += __shfl_xor(bv, off, 64);
    __shared__ int wsb[4];
    if ((t & 63) == 0) wsb[t >> 6] = bv;
    __syncthreads();
    if (t == 0) base_s = wsb[0] + wsb[1] + wsb[2] + wsb[3];

    int i = b * 256 + t;
    s[t] = (i < N) ? deg[i] : 0;
    __syncthreads();
    for (int off = 1; off < 256; off <<= 1) {
        int v = (t >= off) ? s[t - off] : 0;
        __syncthreads();
        s[t] += v;
        __syncthreads();
    }
    if (i < N) row_ptr[i + 1] = s[t] + base_s;
    if (i == 0) row_ptr[0] = 0;
}

// --- fill via full-range packed LDS cursors (zero global atomics): block c
// walks ONLY its own 12500-edge chunk; pos = row_ptr[d] + pfx[c][d] + cur++ ---
__global__ __launch_bounds__(256) void fill_kernel(
    const int* __restrict__ src, const int* __restrict__ dst,
    const int* __restrict__ row_ptr, const unsigned* __restrict__ pfx,
    unsigned short* __restrict__ csr_src) {
    __shared__ unsigned cur[PACK];
    int c = blockIdx.x;
    int tid = threadIdx.x;
    for (int j = tid; j < PACK; j += 256) cur[j] = 0;
    __syncthreads();
    int ebase = c * EPB;
    for (int e = ebase + tid; e < ebase + EPB; e += 256) {
        int s = src[e], d = dst[e];
        int sh = (d & 1) << 4;
        unsigned old = atomicAdd(&cur[d >> 1], 1u << sh);
        int my = (old >> sh) & 0xFFFF;
        int p = (pfx[(size_t)c * PACK + (d >> 1)] >> sh) & 0xFFFF;
        csr_src[row_ptr[d] + p + my] = (unsigned short)s;
    }
}

// --- hs[i] = emb[batch[i]] * norm_src[i] ---
__global__ void gather_kernel(const int* __restrict__ batch, const float* __restrict__ emb,
                              const float* __restrict__ norm_src, float* __restrict__ hs) {
    int gid = blockIdx.x * 256 + threadIdx.x;
    int i = gid >> 5;
    int c = (gid & 31) << 2;
    if (i < N) {
        float s = norm_src[i];
        f4 v = *(const f4*)(emb + (size_t)batch[i] * D + c);
        *(f4*)(hs + (size_t)i * D + c) = v * s;
    }
}

// --- agg (R14 champion): 1 wave/node, 2 edge-groups x 8-deep; bf16 hi/lo out.
// FETCH = compulsory 8 XCD x (25.6 MB table + csr stream) @ ~3.7 TB/s fill.
__global__ void agg_kernel(const int* __restrict__ row_ptr,
                           const unsigned short* __restrict__ csr_src,
                           const float* __restrict__ hs,
                           short* __restrict__ agg_h, short* __restrict__ agg_l) {
    int gid = blockIdx.x * 256 + threadIdx.x;
    int node = gid >> 6;
    if (node >= N) return;
    int lane = threadIdx.x & 63;
    int grp = lane >> 5;
    int col = (lane & 31) << 2;
    int beg = row_ptr[node], end = row_ptr[node + 1];

    f4 a0 = (f4)0.0f, a1 = (f4)0.0f, a2 = (f4)0.0f, a3 = (f4)0.0f;
    f4 a4 = (f4)0.0f, a5 = (f4)0.0f, a6 = (f4)0.0f, a7 = (f4)0.0f;
    int e = beg + grp;
    for (; e + 14 < end; e += 16) {
        int s0 = csr_src[e];
        int s1 = csr_src[e + 2];
        int s2 = csr_src[e + 4];
        int s3 = csr_src[e + 6];
        int s4 = csr_src[e + 8];
        int s5 = csr_src[e + 10];
        int s6 = csr_src[e + 12];
        int s7 = csr_src[e + 14];
        a0 += *(const f4*)(hs + (size_t)s0 * D + col);
        a1 += *(const f4*)(hs + (size_t)s1 * D + col);
        a2 += *(const f4*)(hs + (size_t)s2 * D + col);
        a3 += *(const f4*)(hs + (size_t)s3 * D + col);
        a4 += *(const f4*)(hs + (size_t)s4 * D + col);
        a5 += *(const f4*)(hs + (size_t)s5 * D + col);
        a6 += *(const f4*)(hs + (size_t)s6 * D + col);
        a7 += *(const f4*)(hs + (size_t)s7 * D + col);
    }
    for (; e < end; e += 2)
        a0 += *(const f4*)(hs + (size_t)csr_src[e] * D + col);
    a0 += a1; a2 += a3; a4 += a5; a6 += a7;
    a0 += a2; a4 += a6;
    a0 += a4;

    f4 o;
#pragma unroll
    for (int j = 0; j < 4; ++j)
        o[j] = a0[j] + __shfl_xor(a0[j], 32, 64);
    if (grp == 0) {
        s4 oh, ol;
#pragma unroll
        for (int j = 0; j < 4; ++j) {
            unsigned short h = f32_bf16_rne(o[j]);
            oh[j] = (short)h;
            ol[j] = (short)f32_bf16_rne(o[j] - bf16_f32(h));
        }
        *(s4*)(agg_h + (size_t)node * D + col) = oh;
        *(s4*)(agg_l + (size_t)node * D + col) = ol;
    }
}

// --- W prep: wt[layer][hi/lo][n][k] = bf16 split of W[k][n] (transposed) ---
__global__ void wprep_kernel(const float* __restrict__ W1, const float* __restrict__ W2,
                             const float* __restrict__ W3, short* __restrict__ wt) {
    int idx = blockIdx.x * 256 + threadIdx.x;
    if (idx >= 3 * D * D) return;
    int l = idx >> 14;
    int e = idx & (D * D - 1);
    int n = e >> 7, k = e & 127;
    const float* W = (l == 0) ? W1 : ((l == 1) ? W2 : W3);
    float w = W[(size_t)k * D + n];
    unsigned short h = f32_bf16_rne(w);
    unsigned short lo = f32_bf16_rne(w - bf16_f32(h));
    wt[(size_t)l * 2 * D * D + (size_t)n * D + k] = (short)h;
    wt[(size_t)l * 2 * D * D + D * D + (size_t)n * D + k] = (short)lo;
}

// --- MFMA GEMM (R14): 128x128 per block; 512 thr = 8 waves; 3-term bf16 split ---
__global__ __launch_bounds__(512, 2) void gemm_mfma_kernel(
    const short* __restrict__ Ah, const short* __restrict__ Al,
    const short* __restrict__ wth,
    const float* __restrict__ bias, const float* __restrict__ norm_dst,
    const float* __restrict__ post, float* __restrict__ out) {
    __shared__ short wt_h[D * WT_PITCH];   // 34816 B
    __shared__ short wt_l[D * WT_PITCH];   // 34816 B

    int tid = threadIdx.x;
    const short* gh = wth;
    const short* gl = wth + (size_t)D * D;

#pragma unroll
    for (int it = 0; it < 4; ++it) {
        int c = tid + it * 512;            // 2048 chunks of 8 shorts
        int n = c >> 4, kc = c & 15;
        *(s8*)(&wt_h[n * WT_PITCH + kc * 8]) = *(const s8*)(gh + (size_t)n * D + kc * 8);
        *(s8*)(&wt_l[n * WT_PITCH + kc * 8]) = *(const s8*)(gl + (size_t)n * D + kc * 8);
    }
    __syncthreads();

    int wv = tid >> 6;                     // 0..7
    int lane = tid & 63;
    int lg = lane >> 4;
    int lr = lane & 15;

    int arow = blockIdx.x * MBLK + wv * 16 + lr;
    const short* ahp = Ah + (size_t)arow * D;
    const short* alp = Al + (size_t)arow * D;

    f32x4 acc[8];
#pragma unroll
    for (int nt = 0; nt < 8; ++nt) acc[nt] = (f32x4)0.0f;

#pragma unroll
    for (int kt = 0; kt < 4; ++kt) {
        int ko = kt * 32 + lg * 8;
        s8 ah = *(const s8*)(ahp + ko);
        s8 al = *(const s8*)(alp + ko);
#pragma unroll
        for (int nt = 0; nt < 8; ++nt) {
            int bidx = (nt * 16 + lr) * WT_PITCH + ko;
            s8 bh = *(const s8*)(&wt_h[bidx]);
            s8 bl = *(const s8*)(&wt_l[bidx]);
            acc[nt] = __builtin_amdgcn_mfma_f32_16x16x32_bf16(ah, bh, acc[nt], 0, 0, 0);
            acc[nt] = __builtin_amdgcn_mfma_f32_16x16x32_bf16(al, bh, acc[nt], 0, 0, 0);
            acc[nt] = __builtin_amdgcn_mfma_f32_16x16x32_bf16(ah, bl, acc[nt], 0, 0, 0);
        }
    }

    int r0 = blockIdx.x * MBLK + wv * 16 + lg * 4;
    float nd[4], ps[4];
#pragma unroll
    for (int i = 0; i < 4; ++i) {
        int gr = r0 + i;
        nd[i] = (gr < N) ? norm_dst[gr] : 0.0f;
        ps[i] = (gr < N) ? (post ? post[gr] : 1.0f) : 0.0f;
    }
#pragma unroll
    for (int nt = 0; nt < 8; ++nt) {
        int col = nt * 16 + lr;
        float bv = bias[col];
#pragma unroll
        for (int i = 0; i < 4; ++i) {
            int gr = r0 + i;
            if (gr < N) {
                float v = fmaxf(acc[nt][i] * nd[i] + bv, 0.0f) * ps[i];
                out[(size_t)gr * D + col] = v;
            }
        }
    }
}

extern "C" void kernel_launch(void* const* d_in, const int* in_sizes, int n_in,
                              void* d_out, int out_size, void* d_ws, size_t ws_size,
                              hipStream_t stream) {
    const int*   batch = (const int*)d_in[0];
    const int*   src   = (const int*)d_in[1];
    const int*   dst   = (const int*)d_in[2];
    const float* emb   = (const float*)d_in[3];
    const float* W1    = (const float*)d_in[4];
    const float* b1    = (const float*)d_in[5];
    const float* W2    = (const float*)d_in[6];
    const float* b2    = (const float*)d_in[7];
    const float* W3    = (const float*)d_in[8];
    const float* b3    = (const float*)d_in[9];
    float* out = (float*)d_out;

    // ws layout (4B elems): norm_src[N] | norm_dst[N] | row_ptr[N+1] | csr_src[E ushort]
    //                       | hs[N_PAD*D] | agg_h[N_PAD*D sh] | agg_l[N_PAD*D sh] | wt
    // gemm writes hs in place (agg fully consumed it before gemm runs).
    // Build transients (psrc[64*PACK], pdst[64*PACK], deg_in[N], bsums = 13 MB)
    // alias the agg region: last read by fill, before agg layer-1 writes agg.
    // Entirely atomic-free build -> no memsets needed (all buffers fully written).
    float*          norm_src = (float*)d_ws;
    float*          norm_dst = norm_src + N;
    int*            row_ptr  = (int*)(norm_dst + N);
    unsigned short* csr_src  = (unsigned short*)(row_ptr + (N + 1));
    float*          hs       = (float*)(csr_src + E) + 2;  // 16B alignment
    short*          agg_h    = (short*)(hs + (size_t)N_PAD * D);
    short*          agg_l    = agg_h + (size_t)N_PAD * D;
    short*          wt       = agg_l + (size_t)N_PAD * D;
    unsigned*       psrc     = (unsigned*)agg_h;               // transient 64*PACK
    unsigned*       pdst     = psrc + (size_t)HG * PACK;       // transient 64*PACK
    int*            deg_in   = (int*)(pdst + (size_t)HG * PACK);
    int*            bsums    = deg_in + N;

    hist_kernel<<<2 * HG, 256, 0, stream>>>(src, dst, psrc, pdst);
    reduce_norm_kernel<<<SCAN_NB, 256, 0, stream>>>(psrc, pdst, norm_src, norm_dst,
                                                    deg_in, bsums);
    prefix_kernel<<<(PACK + 255) / 256, 256, 0, stream>>>(pdst);
    scan_final_kernel<<<SCAN_NB, 256, 0, stream>>>(deg_in, bsums, row_ptr);
    fill_kernel<<<HG, 256, 0, stream>>>(src, dst, row_ptr, pdst, csr_src);
    gather_kernel<<<((size_t)N * 32 + 255) / 256, 256, 0, stream>>>(batch, emb,
                                                                    norm_src, hs);
    wprep_kernel<<<(3 * D * D + 255) / 256, 256, 0, stream>>>(W1, W2, W3, wt);

    const float* bs[3] = {b1, b2, b3};
    for (int l = 0; l < 3; ++l) {
        bool last = (l == 2);
        agg_kernel<<<((size_t)N * 64 + 255) / 256, 256, 0, stream>>>(
            row_ptr, csr_src, hs, agg_h, agg_l);
        gemm_mfma_kernel<<<GRID_M, 512, 0, stream>>>(
            agg_h, agg_l, wt + (size_t)l * 2 * D * D, bs[l], norm_dst,
            last ? nullptr : norm_src,
            last ? out : hs);
    }
}

// Round 18
// 319.827 us; speedup vs baseline: 2.6670x; 1.0436x over previous
//
#include <hip/hip_runtime.h>
#include <math.h>

typedef float f4 __attribute__((ext_vector_type(4)));
typedef float f32x4 __attribute__((ext_vector_type(4)));
typedef short s8 __attribute__((ext_vector_type(8)));  // 8 bf16 (4 VGPRs)
typedef short s4 __attribute__((ext_vector_type(4)));  // 4 bf16 (2 VGPRs)

static constexpr int N = 50000;
static constexpr int E = 800000;
static constexpr int D = 128;
static constexpr int MBLK = 128;                       // gemm rows/block
static constexpr int GRID_M = (N + MBLK - 1) / MBLK;   // 391
static constexpr int N_PAD = GRID_M * MBLK;            // 50048
static constexpr int WT_PITCH = 136;                   // LDS pad
static constexpr int HG = 64;                          // hist/fill chunks
static constexpr int EPB = E / HG;                     // 12500 edges/chunk
static constexpr int PACK = N / 2;                     // 25000 packed u32 (2 u16)
static constexpr int RP_NB = (PACK + 255) / 256;       // 98 pair-blocks

__device__ inline unsigned short f32_bf16_rne(float x) {
    unsigned u = __float_as_uint(x);
    return (unsigned short)((u + 0x7FFF + ((u >> 16) & 1)) >> 16);
}
__device__ inline float bf16_f32(unsigned short h) {
    return __uint_as_float((unsigned)h << 16);
}

// --- full-range LDS histogram (packed u16 pairs, 100 KB LDS, zero global
// atomics): block b<HG histograms src over its 12500-edge chunk; b>=HG dst.
// 512 threads: halves the fixed LDS init/writeback loops vs 256.
__global__ __launch_bounds__(512) void hist_kernel(
    const int* __restrict__ src, const int* __restrict__ dst,
    unsigned* __restrict__ psrc, unsigned* __restrict__ pdst) {
    __shared__ unsigned h[PACK];
    int b = blockIdx.x;
    int tid = threadIdx.x;
    bool isd = b >= HG;
    int bb = isd ? b - HG : b;
    const int* ids = isd ? dst : src;
    for (int j = tid; j < PACK; j += 512) h[j] = 0;
    __syncthreads();
    int ebase = bb * EPB;
    for (int e = ebase + tid; e < ebase + EPB; e += 512) {
        int v = ids[e];
        atomicAdd(&h[v >> 1], 1u << ((v & 1) << 4));
    }
    __syncthreads();
    unsigned* out = (isd ? pdst : psrc) + (size_t)bb * PACK;
    for (int j = tid; j < PACK; j += 512) out[j] = h[j];
}

// --- merged reduce+prefix: thread per packed u32 (2 nodes). One pass over the
// 64 chunk-partials computes degrees + norms AND rewrites pdst into per-chunk
// exclusive prefixes. bsums[b] = deg_in sum over block's 512 nodes.
__global__ __launch_bounds__(256) void reduce_prefix_kernel(
    const unsigned* __restrict__ psrc, unsigned* __restrict__ pdst,
    float* __restrict__ norm_src, float* __restrict__ norm_dst,
    int* __restrict__ deg_in, int* __restrict__ bsums) {
    int j = blockIdx.x * 256 + threadIdx.x;
    int din0 = 0, din1 = 0;
    if (j < PACK) {
        int dout0 = 0, dout1 = 0;
        unsigned run0 = 0, run1 = 0;
#pragma unroll 8
        for (int c = 0; c < HG; ++c) {
            unsigned us = psrc[(size_t)c * PACK + j];
            dout0 += us & 0xFFFF;
            dout1 += us >> 16;
            unsigned ud = pdst[(size_t)c * PACK + j];
            pdst[(size_t)c * PACK + j] = run0 | (run1 << 16);
            run0 += ud & 0xFFFF;
            run1 += ud >> 16;
        }
        din0 = (int)run0;
        din1 = (int)run1;
        int i0 = 2 * j, i1 = 2 * j + 1;
        norm_src[i0] = rsqrtf(fmaxf((float)dout0, 1.0f));
        norm_src[i1] = rsqrtf(fmaxf((float)dout1, 1.0f));
        norm_dst[i0] = rsqrtf(fmaxf((float)din0, 1.0f));
        norm_dst[i1] = rsqrtf(fmaxf((float)din1, 1.0f));
        deg_in[i0] = din0;
        deg_in[i1] = din1;
    }
    int v = din0 + din1;
#pragma unroll
    for (int off = 1; off < 64; off <<= 1) v += __shfl_xor(v, off, 64);
    __shared__ int ws[4];
    if ((threadIdx.x & 63) == 0) ws[threadIdx.x >> 6] = v;
    __syncthreads();
    if (threadIdx.x == 0) bsums[blockIdx.x] = ws[0] + ws[1] + ws[2] + ws[3];
}

// --- scan final (pair-based): thread t handles pair j = b*256+t (nodes 2j,2j+1).
// Block base = sum of bsums below b (98 entries, in-block). N is even.
__global__ __launch_bounds__(256) void scan_final_kernel(const int* __restrict__ deg,
                                                         const int* __restrict__ bsums,
                                                         int* __restrict__ row_ptr) {
    __shared__ int s[256];
    __shared__ int base_s;
    int b = blockIdx.x, t = threadIdx.x;

    int bv = (t < b && t < RP_NB) ? bsums[t] : 0;
#pragma unroll
    for (int off = 1; off < 64; off <<= 1) bv += __shfl_xor(bv, off, 64);
    __shared__ int wsb[4];
    if ((t & 63) == 0) wsb[t >> 6] = bv;
    __syncthreads();
    if (t == 0) base_s = wsb[0] + wsb[1] + wsb[2] + wsb[3];

    int j = b * 256 + t;
    int d0 = (j < PACK) ? deg[2 * j] : 0;
    int d1 = (j < PACK) ? deg[2 * j + 1] : 0;
    s[t] = d0 + d1;
    __syncthreads();
    for (int off = 1; off < 256; off <<= 1) {
        int v = (t >= off) ? s[t - off] : 0;
        __syncthreads();
        s[t] += v;
        __syncthreads();
    }
    if (j < PACK) {
        int pend = s[t] + base_s;          // end of pair j
        row_ptr[2 * j + 2] = pend;
        row_ptr[2 * j + 1] = pend - d1;
    }
    if (j == 0) row_ptr[0] = 0;
}

// --- fill via full-range packed LDS cursors (zero global atomics), 512 thr ---
__global__ __launch_bounds__(512) void fill_kernel(
    const int* __restrict__ src, const int* __restrict__ dst,
    const int* __restrict__ row_ptr, const unsigned* __restrict__ pfx,
    unsigned short* __restrict__ csr_src) {
    __shared__ unsigned cur[PACK];
    int c = blockIdx.x;
    int tid = threadIdx.x;
    for (int j = tid; j < PACK; j += 512) cur[j] = 0;
    __syncthreads();
    int ebase = c * EPB;
    for (int e = ebase + tid; e < ebase + EPB; e += 512) {
        int s = src[e], d = dst[e];
        int sh = (d & 1) << 4;
        unsigned old = atomicAdd(&cur[d >> 1], 1u << sh);
        int my = (old >> sh) & 0xFFFF;
        int p = (pfx[(size_t)c * PACK + (d >> 1)] >> sh) & 0xFFFF;
        csr_src[row_ptr[d] + p + my] = (unsigned short)s;
    }
}

// --- hs[i] = emb[batch[i]] * norm_src[i] ---
__global__ void gather_kernel(const int* __restrict__ batch, const float* __restrict__ emb,
                              const float* __restrict__ norm_src, float* __restrict__ hs) {
    int gid = blockIdx.x * 256 + threadIdx.x;
    int i = gid >> 5;
    int c = (gid & 31) << 2;
    if (i < N) {
        float s = norm_src[i];
        f4 v = *(const f4*)(emb + (size_t)batch[i] * D + c);
        *(f4*)(hs + (size_t)i * D + c) = v * s;
    }
}

// --- agg (champion): 1 wave/node, 2 edge-groups x 8-deep; bf16 hi/lo out.
// FETCH = compulsory 8 XCD x (25.6 MB table + csr stream) @ ~3.7 TB/s fill.
__global__ void agg_kernel(const int* __restrict__ row_ptr,
                           const unsigned short* __restrict__ csr_src,
                           const float* __restrict__ hs,
                           short* __restrict__ agg_h, short* __restrict__ agg_l) {
    int gid = blockIdx.x * 256 + threadIdx.x;
    int node = gid >> 6;
    if (node >= N) return;
    int lane = threadIdx.x & 63;
    int grp = lane >> 5;
    int col = (lane & 31) << 2;
    int beg = row_ptr[node], end = row_ptr[node + 1];

    f4 a0 = (f4)0.0f, a1 = (f4)0.0f, a2 = (f4)0.0f, a3 = (f4)0.0f;
    f4 a4 = (f4)0.0f, a5 = (f4)0.0f, a6 = (f4)0.0f, a7 = (f4)0.0f;
    int e = beg + grp;
    for (; e + 14 < end; e += 16) {
        int s0 = csr_src[e];
        int s1 = csr_src[e + 2];
        int s2 = csr_src[e + 4];
        int s3 = csr_src[e + 6];
        int s4 = csr_src[e + 8];
        int s5 = csr_src[e + 10];
        int s6 = csr_src[e + 12];
        int s7 = csr_src[e + 14];
        a0 += *(const f4*)(hs + (size_t)s0 * D + col);
        a1 += *(const f4*)(hs + (size_t)s1 * D + col);
        a2 += *(const f4*)(hs + (size_t)s2 * D + col);
        a3 += *(const f4*)(hs + (size_t)s3 * D + col);
        a4 += *(const f4*)(hs + (size_t)s4 * D + col);
        a5 += *(const f4*)(hs + (size_t)s5 * D + col);
        a6 += *(const f4*)(hs + (size_t)s6 * D + col);
        a7 += *(const f4*)(hs + (size_t)s7 * D + col);
    }
    for (; e < end; e += 2)
        a0 += *(const f4*)(hs + (size_t)csr_src[e] * D + col);
    a0 += a1; a2 += a3; a4 += a5; a6 += a7;
    a0 += a2; a4 += a6;
    a0 += a4;

    f4 o;
#pragma unroll
    for (int j = 0; j < 4; ++j)
        o[j] = a0[j] + __shfl_xor(a0[j], 32, 64);
    if (grp == 0) {
        s4 oh, ol;
#pragma unroll
        for (int j = 0; j < 4; ++j) {
            unsigned short h = f32_bf16_rne(o[j]);
            oh[j] = (short)h;
            ol[j] = (short)f32_bf16_rne(o[j] - bf16_f32(h));
        }
        *(s4*)(agg_h + (size_t)node * D + col) = oh;
        *(s4*)(agg_l + (size_t)node * D + col) = ol;
    }
}

// --- W prep: wt[layer][hi/lo][n][k] = bf16 split of W[k][n] (transposed) ---
__global__ void wprep_kernel(const float* __restrict__ W1, const float* __restrict__ W2,
                             const float* __restrict__ W3, short* __restrict__ wt) {
    int idx = blockIdx.x * 256 + threadIdx.x;
    if (idx >= 3 * D * D) return;
    int l = idx >> 14;
    int e = idx & (D * D - 1);
    int n = e >> 7, k = e & 127;
    const float* W = (l == 0) ? W1 : ((l == 1) ? W2 : W3);
    float w = W[(size_t)k * D + n];
    unsigned short h = f32_bf16_rne(w);
    unsigned short lo = f32_bf16_rne(w - bf16_f32(h));
    wt[(size_t)l * 2 * D * D + (size_t)n * D + k] = (short)h;
    wt[(size_t)l * 2 * D * D + D * D + (size_t)n * D + k] = (short)lo;
}

// --- MFMA GEMM (champion): 128x128 per block; 512 thr = 8 waves; 3-term split ---
__global__ __launch_bounds__(512, 2) void gemm_mfma_kernel(
    const short* __restrict__ Ah, const short* __restrict__ Al,
    const short* __restrict__ wth,
    const float* __restrict__ bias, const float* __restrict__ norm_dst,
    const float* __restrict__ post, float* __restrict__ out) {
    __shared__ short wt_h[D * WT_PITCH];   // 34816 B
    __shared__ short wt_l[D * WT_PITCH];   // 34816 B

    int tid = threadIdx.x;
    const short* gh = wth;
    const short* gl = wth + (size_t)D * D;

#pragma unroll
    for (int it = 0; it < 4; ++it) {
        int c = tid + it * 512;            // 2048 chunks of 8 shorts
        int n = c >> 4, kc = c & 15;
        *(s8*)(&wt_h[n * WT_PITCH + kc * 8]) = *(const s8*)(gh + (size_t)n * D + kc * 8);
        *(s8*)(&wt_l[n * WT_PITCH + kc * 8]) = *(const s8*)(gl + (size_t)n * D + kc * 8);
    }
    __syncthreads();

    int wv = tid >> 6;                     // 0..7
    int lane = tid & 63;
    int lg = lane >> 4;
    int lr = lane & 15;

    int arow = blockIdx.x * MBLK + wv * 16 + lr;
    const short* ahp = Ah + (size_t)arow * D;
    const short* alp = Al + (size_t)arow * D;

    f32x4 acc[8];
#pragma unroll
    for (int nt = 0; nt < 8; ++nt) acc[nt] = (f32x4)0.0f;

#pragma unroll
    for (int kt = 0; kt < 4; ++kt) {
        int ko = kt * 32 + lg * 8;
        s8 ah = *(const s8*)(ahp + ko);
        s8 al = *(const s8*)(alp + ko);
#pragma unroll
        for (int nt = 0; nt < 8; ++nt) {
            int bidx = (nt * 16 + lr) * WT_PITCH + ko;
            s8 bh = *(const s8*)(&wt_h[bidx]);
            s8 bl = *(const s8*)(&wt_l[bidx]);
            acc[nt] = __builtin_amdgcn_mfma_f32_16x16x32_bf16(ah, bh, acc[nt], 0, 0, 0);
            acc[nt] = __builtin_amdgcn_mfma_f32_16x16x32_bf16(al, bh, acc[nt], 0, 0, 0);
            acc[nt] = __builtin_amdgcn_mfma_f32_16x16x32_bf16(ah, bl, acc[nt], 0, 0, 0);
        }
    }

    int r0 = blockIdx.x * MBLK + wv * 16 + lg * 4;
    float nd[4], ps[4];
#pragma unroll
    for (int i = 0; i < 4; ++i) {
        int gr = r0 + i;
        nd[i] = (gr < N) ? norm_dst[gr] : 0.0f;
        ps[i] = (gr < N) ? (post ? post[gr] : 1.0f) : 0.0f;
    }
#pragma unroll
    for (int nt = 0; nt < 8; ++nt) {
        int col = nt * 16 + lr;
        float bv = bias[col];
#pragma unroll
        for (int i = 0; i < 4; ++i) {
            int gr = r0 + i;
            if (gr < N) {
                float v = fmaxf(acc[nt][i] * nd[i] + bv, 0.0f) * ps[i];
                out[(size_t)gr * D + col] = v;
            }
        }
    }
}

extern "C" void kernel_launch(void* const* d_in, const int* in_sizes, int n_in,
                              void* d_out, int out_size, void* d_ws, size_t ws_size,
                              hipStream_t stream) {
    const int*   batch = (const int*)d_in[0];
    const int*   src   = (const int*)d_in[1];
    const int*   dst   = (const int*)d_in[2];
    const float* emb   = (const float*)d_in[3];
    const float* W1    = (const float*)d_in[4];
    const float* b1    = (const float*)d_in[5];
    const float* W2    = (const float*)d_in[6];
    const float* b2    = (const float*)d_in[7];
    const float* W3    = (const float*)d_in[8];
    const float* b3    = (const float*)d_in[9];
    float* out = (float*)d_out;

    // ws layout (4B elems): norm_src[N] | norm_dst[N] | row_ptr[N+1] | csr_src[E ushort]
    //                       | hs[N_PAD*D] | agg_h[N_PAD*D sh] | agg_l[N_PAD*D sh] | wt
    // gemm writes hs in place (agg fully consumed it before gemm runs).
    // Build transients (psrc/pdst 64*PACK each, deg_in[N], bsums) alias the agg
    // region: last read by fill, before agg layer-1 writes agg. Atomic-free
    // build -> no memsets (all buffers fully overwritten every launch).
    float*          norm_src = (float*)d_ws;
    float*          norm_dst = norm_src + N;
    int*            row_ptr  = (int*)(norm_dst + N);
    unsigned short* csr_src  = (unsigned short*)(row_ptr + (N + 1));
    float*          hs       = (float*)(csr_src + E) + 2;  // 16B alignment
    short*          agg_h    = (short*)(hs + (size_t)N_PAD * D);
    short*          agg_l    = agg_h + (size_t)N_PAD * D;
    short*          wt       = agg_l + (size_t)N_PAD * D;
    unsigned*       psrc     = (unsigned*)agg_h;               // transient 64*PACK
    unsigned*       pdst     = psrc + (size_t)HG * PACK;       // transient 64*PACK
    int*            deg_in   = (int*)(pdst + (size_t)HG * PACK);
    int*            bsums    = deg_in + N;

    hist_kernel<<<2 * HG, 512, 0, stream>>>(src, dst, psrc, pdst);
    reduce_prefix_kernel<<<RP_NB, 256, 0, stream>>>(psrc, pdst, norm_src, norm_dst,
                                                    deg_in, bsums);
    scan_final_kernel<<<RP_NB, 256, 0, stream>>>(deg_in, bsums, row_ptr);
    fill_kernel<<<HG, 512, 0, stream>>>(src, dst, row_ptr, pdst, csr_src);
    gather_kernel<<<((size_t)N * 32 + 255) / 256, 256, 0, stream>>>(batch, emb,
                                                                    norm_src, hs);
    wprep_kernel<<<(3 * D * D + 255) / 256, 256, 0, stream>>>(W1, W2, W3, wt);

    const float* bs[3] = {b1, b2, b3};
    for (int l = 0; l < 3; ++l) {
        bool last = (l == 2);
        agg_kernel<<<((size_t)N * 64 + 255) / 256, 256, 0, stream>>>(
            row_ptr, csr_src, hs, agg_h, agg_l);
        gemm_mfma_kernel<<<GRID_M, 512, 0, stream>>>(
            agg_h, agg_l, wt + (size_t)l * 2 * D * D, bs[l], norm_dst,
            last ? nullptr : norm_src,
            last ? out : hs);
    }
}